// Round 9
// baseline (5384.295 us; speedup 1.0000x reference)
//
#include <hip/hip_runtime.h>

#define NE 400
#define NIN 784
#define BB 512
#define TT 50

#define KC1 14         // gemm1 K-chunks over input dim (784 = 14*56)
#define KCH1 56
#define KT1 8          // gemm1 inner k-tile
#define KC2 8          // gemm2 K-chunks over concat batch (1024 = 8*128)
#define KCH2 128
#define NPATCH 49      // 7 e-tiles x 7 i-tiles

constexpr float C_KE     = (float)(0.5 / 100.0);
constexpr float C_KI     = (float)(0.5 / 10.0);
constexpr float C_GSE    = 0.5f;
constexpr float C_GSI    = 0.25f;
constexpr float C_DECTH  = (float)(1.0 - 0.5 / 1e7);
constexpr float C_DEC1   = (float)(1.0 - 0.5 / 20.0);
constexpr float C_DEC2   = (float)(1.0 - 0.5 / 40.0);
constexpr float C_DECPRE = (float)(1.0 - 0.5 / 20.0);
constexpr float C_NUPRE  = (float)0.0001;
constexpr float C_NUPOST = 0.01f;

// Shared by init (USE_PARTS=false: W=clip(W0), d=1) and g2f epilogue.
// Patch (ex,iy): rows ex*64..+64, f4-cols iy*32..+32. 256 threads:
// e_l=lid>>2, lg=lid&3 covers 8 f4 each. Rowsum association identical in both.
template <bool USE_PARTS>
__device__ __forceinline__ void patch_update(const float* __restrict__ Wsrc,
                                             float* __restrict__ Wdst,
                                             const float* __restrict__ part,
                                             const float* __restrict__ dbuf,
                                             float* __restrict__ rs,
                                             int ex, int iy, int lid) {
    int e_l = lid >> 2, lg = lid & 3;
    int e = ex * 64 + e_l;
    float rsum = 0.f;
    if (e < NE) {
        float dv = USE_PARTS ? dbuf[e] : 1.0f;
#pragma unroll
        for (int j8 = 0; j8 < 8; j8++) {
            int f4 = iy * 32 + lg * 8 + j8;
            if (f4 < 196) {
                int off = e * NIN + f4 * 4;
                float4 w = *(const float4*)&Wsrc[off];
                float4 a = make_float4(w.x / dv, w.y / dv, w.z / dv, w.w / dv);
                if (USE_PARTS) {
#pragma unroll
                    for (int c = 0; c < KC2; c++) {
                        float4 pp = *(const float4*)&part[(size_t)c * NE * NIN + off];
                        a.x += pp.x; a.y += pp.y; a.z += pp.z; a.w += pp.w;
                    }
                }
                a.x = fminf(fmaxf(a.x, 0.f), 1.f);
                a.y = fminf(fmaxf(a.y, 0.f), 1.f);
                a.z = fminf(fmaxf(a.z, 0.f), 1.f);
                a.w = fminf(fmaxf(a.w, 0.f), 1.f);
                *(float4*)&Wdst[off] = a;
                rsum += (a.x + a.y) + (a.z + a.w);
            }
        }
    }
    float v = rsum;
    v += __shfl_down(v, 2, 64);
    v += __shfl_down(v, 1, 64);
    if (lg == 0 && e < NE) rs[iy * NE + e] = v;
}

// one launch: state init + cnt zero + W0 copy/rowsum patches + tr0 copy
__global__ __launch_bounds__(256) void k_init(const float* __restrict__ W0,
                                              float* __restrict__ W,
                                              float* __restrict__ rs,
                                              int* __restrict__ cnt,
                                              const float* __restrict__ x0,
                                              float* __restrict__ tr,
                                              float* g_ine, float* g_ei, float* g_ie,
                                              float* Iie, float* mem_e, float* rc_e,
                                              float* mem_i, float* rc_i, float* theta,
                                              float* tp1, float* tp2) {
    int bid = blockIdx.x, lid = threadIdx.x;
    if (bid < 800) {
        int i = bid * 256 + lid;
        g_ine[i] = 0.f; g_ei[i] = 0.f; g_ie[i] = 0.f; Iie[i] = 0.f;
        mem_e[i] = -65.0f; rc_e[i] = 0.f;
        mem_i[i] = -60.0f; rc_i[i] = 0.f;
        theta[i] = 20.0f; tp1[i] = 0.f; tp2[i] = 0.f;
        if (bid == 0 && lid < NPATCH) cnt[lid] = 0;
    } else if (bid < 800 + NPATCH) {
        int pid = bid - 800;
        patch_update<false>(W0, W, nullptr, nullptr, rs, pid / 7, pid % 7, lid);
    } else {
        int base = (bid - 800 - NPATCH) * 2048 + lid * 4;
        *(float4*)&tr[base] = *(const float4*)&x0[base];
    }
}

// gemm1 partials + pre-trace. blocks [0,392): tile 128(b) x 64(e), per-thread 8x4,
// k-tile 8, chunk 56, double-buffered LDS (1 sync/tile). blocks [392,588): trace.
__global__ __launch_bounds__(256) void k_g1(const float* __restrict__ x,
                                            const float* __restrict__ W,
                                            float* __restrict__ dgp,
                                            float* __restrict__ tr, int t) {
    __shared__ float sA[2][KT1][132];   // [buf][k][b 128]
    __shared__ float sB[2][KT1][68];    // [buf][k][e 64]
    const int lid = threadIdx.x;
    int j = blockIdx.x;
    if (j >= 392) {
        if (t == 0) return;
        int base = (j - 392) * 2048 + lid * 4;
        float4 xv = *(const float4*)&x[base];
        float4 tv = *(const float4*)&tr[base];
        float4 o;
        o.x = (xv.x > 0.9f) ? 1.f : tv.x * C_DECPRE;
        o.y = (xv.y > 0.9f) ? 1.f : tv.y * C_DECPRE;
        o.z = (xv.z > 0.9f) ? 1.f : tv.z * C_DECPRE;
        o.w = (xv.w > 0.9f) ? 1.f : tv.w * C_DECPRE;
        *(float4*)&tr[base] = o;
        return;
    }
    const int kz = j / 28, rem = j % 28;
    const int by = rem / 7, ex = rem % 7;
    const int e0 = ex * 64, b0 = by * 128, kb = kz * KCH1;
    const int tx = lid & 15, ty = lid >> 4;
    const int xr = lid >> 1, xc = (lid & 1) * 4;   // x stage: 128 rows x 8k, f4
    const int wr = lid >> 2, wc = (lid & 3) * 2;   // W stage: 64 rows x 8k, f2
    const bool wok = (e0 + wr) < NE;

    float acc[8][4];
#pragma unroll
    for (int p = 0; p < 8; p++)
#pragma unroll
        for (int q = 0; q < 4; q++) acc[p][q] = 0.f;

    float4 xv;
    float2 wv;
    auto ld = [&](int kt) {
        int k0 = kb + kt * KT1;
        xv = *(const float4*)&x[(b0 + xr) * NIN + k0 + xc];
        wv = wok ? *(const float2*)&W[(e0 + wr) * NIN + k0 + wc]
                 : make_float2(0.f, 0.f);
    };
    auto st = [&](int buf) {
        sA[buf][xc + 0][xr] = xv.x; sA[buf][xc + 1][xr] = xv.y;
        sA[buf][xc + 2][xr] = xv.z; sA[buf][xc + 3][xr] = xv.w;
        sB[buf][wc + 0][wr] = wv.x; sB[buf][wc + 1][wr] = wv.y;
    };

    ld(0); st(0);
    __syncthreads();
    const int NKT = KCH1 / KT1;
    for (int kt = 0; kt < NKT; kt++) {
        int cur = kt & 1;
        if (kt + 1 < NKT) ld(kt + 1);
#pragma unroll
        for (int k = 0; k < KT1; k++) {
            float4 a0 = *(const float4*)&sA[cur][k][ty * 8];
            float4 a1 = *(const float4*)&sA[cur][k][ty * 8 + 4];
            float4 bv = *(const float4*)&sB[cur][k][tx * 4];
            float a[8] = {a0.x, a0.y, a0.z, a0.w, a1.x, a1.y, a1.z, a1.w};
            float b[4] = {bv.x, bv.y, bv.z, bv.w};
#pragma unroll
            for (int p = 0; p < 8; p++)
#pragma unroll
                for (int q = 0; q < 4; q++) acc[p][q] += a[p] * b[q];
        }
        if (kt + 1 < NKT) st(cur ^ 1);
        __syncthreads();
    }
    if (e0 + tx * 4 < NE) {
        float* basep = dgp + (size_t)kz * BB * NE;
#pragma unroll
        for (int p = 0; p < 8; p++) {
            int row = b0 + ty * 8 + p;
            *(float4*)&basep[row * NE + e0 + tx * 4] =
                make_float4(acc[p][0], acc[p][1], acc[p][2], acc[p][3]);
        }
    }
}

// pure LIF phase; d computed from rs partials; block 0 publishes dbuf for g2f
__global__ __launch_bounds__(512) void k_mid(const float* __restrict__ dgp,
                                             const float* __restrict__ rs,
                                             float* __restrict__ dbuf,
                                             float* g_ine, float* g_ei, float* g_ie,
                                             float* Iie, float* mem_e, float* rc_e,
                                             float* mem_i, float* rc_i, float* theta,
                                             float* tp1, float* tp2,
                                             float* __restrict__ A1s,
                                             float* __restrict__ A2s,
                                             float* __restrict__ out_t) {
    int b = blockIdx.x;
    int e = threadIdx.x;
    __shared__ float red[8];
    int idx = b * NE + e;

    float spk_i = 0.f, spk_e = 0.f;
    float g1 = 0.f, me = 0.f, re = 0.f, th = 0.f, g2 = 0.f, mi = 0.f, ri = 0.f;

    if (e < NE) {
        float dsum = 0.f;
#pragma unroll
        for (int iy = 0; iy < 7; iy++) dsum += rs[iy * NE + e];
        float dv = dsum / 78.4f;
        if (b == 0) dbuf[e] = dv;
        float dg = 0.f;
#pragma unroll
        for (int c = 0; c < KC1; c++) dg += dgp[(size_t)c * BB * NE + idx];
        dg = dg / dv;
        g1 = g_ine[idx]; me = mem_e[idx]; re = rc_e[idx];
        th = theta[idx];
        float Ii = Iie[idx];
        float I_in = g1 * (0.0f - me);
        g1 = g1 + (dg - g1) * C_GSE;
        bool act = (re <= 0.0f);
        float I = I_in + Ii;
        if (act) me = me + ((-65.0f - me) + I) * C_KE;
        re = fmaxf(re - 0.5f, 0.0f);
        float thr = -72.0f + th;
        spk_e = (act && (me > thr)) ? 1.0f : 0.0f;
        if (spk_e > 0.0f) { me = -65.0f; re = 5.0f; }
        float dgei = spk_e * 10.4f;
        g2 = g_ei[idx]; mi = mem_i[idx]; ri = rc_i[idx];
        float I_ei = g2 * (0.0f - mi);
        g2 = g2 + (dgei - g2) * C_GSE;
        bool ai = (ri <= 0.0f);
        if (ai) mi = mi + ((-60.0f - mi) + I_ei) * C_KI;
        ri = fmaxf(ri - 0.5f, 0.0f);
        spk_i = (ai && (mi > -40.0f)) ? 1.0f : 0.0f;
        if (spk_i > 0.0f) { mi = -45.0f; ri = 2.0f; }
    }
    float v = spk_i;
#pragma unroll
    for (int o = 32; o > 0; o >>= 1) v += __shfl_down(v, o, 64);
    if ((e & 63) == 0) red[e >> 6] = v;
    __syncthreads();
    float S = ((red[0] + red[1]) + (red[2] + red[3])) +
              ((red[4] + red[5]) + (red[6] + red[7]));   // integer-valued: exact
    if (e < NE) {
        float dgie = 17.0f * (S - spk_i);
        float g3 = g_ie[idx];
        float Iie_new = g3 * (-100.0f - me);
        g3 = g3 + (dgie - g3) * C_GSI;
        float th2 = th * C_DECTH + 0.05f * spk_e;
        float r1 = tp1[idx] * C_DEC1;
        float r2 = tp2[idx] * C_DEC2;
        bool fired = spk_e > 0.9f;
        A1s[idx] = C_NUPRE * r1;
        A2s[idx] = C_NUPOST * (spk_e * r2);
        tp1[idx] = fired ? 1.0f : r1;
        tp2[idx] = fired ? 1.0f : r2;
        g_ine[idx] = g1; g_ei[idx] = g2; g_ie[idx] = g3; Iie[idx] = Iie_new;
        mem_e[idx] = me; rc_e[idx] = re; mem_i[idx] = mi; rc_i[idx] = ri;
        theta[idx] = th2;
        out_t[idx] = spk_e;
    }
}

// gemm2 + fused W-update: partials then last-block-per-patch epilogue.
// tile 64(e) x 128(i), per-thread 4x8 quadrants, k-tile 16, chunk 128, dbuf LDS.
__global__ __launch_bounds__(256) void k_g2f(const float* __restrict__ A1s,
                                             const float* __restrict__ A2s,
                                             const float* __restrict__ x,
                                             const float* __restrict__ tr,
                                             float* __restrict__ part,
                                             float* __restrict__ W,
                                             const float* __restrict__ dbuf,
                                             float* __restrict__ rs,
                                             int* __restrict__ cnt) {
    __shared__ float sA[2][16][68];    // [buf][k][e 64]
    __shared__ float sB[2][16][132];   // [buf][k][i 128]
    const int lid = threadIdx.x;
    const int tx = lid & 15, ty = lid >> 4;
    const int ex = blockIdx.x, iy = blockIdx.y;
    const int e0 = ex * 64, i0 = iy * 128;
    const int kb = blockIdx.z * KCH2;
    const int kr = lid >> 4;            // 0..15 (k row)
    const int jc = (lid & 15) * 4;      // col offset 0..60
    const float4 z4 = make_float4(0.f, 0.f, 0.f, 0.f);

    float acc[4][2][4];
#pragma unroll
    for (int p = 0; p < 4; p++)
#pragma unroll
        for (int h = 0; h < 2; h++)
#pragma unroll
            for (int q = 0; q < 4; q++) acc[p][h][q] = 0.f;

    float4 av_, bv0_, bv1_;
    auto ld = [&](int kt) {
        int gb = kb + kt * 16 + kr;
        av_ = (e0 + jc < NE)
                  ? ((gb < BB) ? *(const float4*)&A1s[gb * NE + e0 + jc]
                               : *(const float4*)&A2s[(gb - BB) * NE + e0 + jc])
                  : z4;
        const float* src; int rb;
        if (gb < BB) { src = x; rb = gb; } else { src = tr; rb = gb - BB; }
        int c1 = i0 + jc, c2 = i0 + 64 + jc;
        bv0_ = (c1 < NIN) ? *(const float4*)&src[rb * NIN + c1] : z4;
        bv1_ = (c2 < NIN) ? *(const float4*)&src[rb * NIN + c2] : z4;
    };
    auto st = [&](int buf) {
        *(float4*)&sA[buf][kr][jc] = av_;
        *(float4*)&sB[buf][kr][jc] = bv0_;
        *(float4*)&sB[buf][kr][64 + jc] = bv1_;
    };

    ld(0); st(0);
    __syncthreads();
    const int NKT = KCH2 / 16;
    for (int kt = 0; kt < NKT; kt++) {
        int cur = kt & 1;
        if (kt + 1 < NKT) ld(kt + 1);
#pragma unroll
        for (int k = 0; k < 16; k++) {
            float4 av = *(const float4*)&sA[cur][k][ty * 4];
            float4 b0v = *(const float4*)&sB[cur][k][tx * 4];
            float4 b1v = *(const float4*)&sB[cur][k][64 + tx * 4];
            float a[4] = {av.x, av.y, av.z, av.w};
            float bq0[4] = {b0v.x, b0v.y, b0v.z, b0v.w};
            float bq1[4] = {b1v.x, b1v.y, b1v.z, b1v.w};
#pragma unroll
            for (int p = 0; p < 4; p++)
#pragma unroll
                for (int q = 0; q < 4; q++) {
                    acc[p][0][q] += a[p] * bq0[q];
                    acc[p][1][q] += a[p] * bq1[q];
                }
        }
        if (kt + 1 < NKT) st(cur ^ 1);
        __syncthreads();
    }
    {
        float* basep = part + (size_t)blockIdx.z * NE * NIN;
        int c1 = i0 + tx * 4, c2 = i0 + 64 + tx * 4;
#pragma unroll
        for (int p = 0; p < 4; p++) {
            int row = e0 + ty * 4 + p;
            if (row < NE) {
                if (c1 < NIN)
                    *(float4*)&basep[row * NIN + c1] = make_float4(
                        acc[p][0][0], acc[p][0][1], acc[p][0][2], acc[p][0][3]);
                if (c2 < NIN)
                    *(float4*)&basep[row * NIN + c2] = make_float4(
                        acc[p][1][0], acc[p][1][1], acc[p][1][2], acc[p][1][3]);
            }
        }
    }
    // last-block-per-patch W update (deterministic c-order sum)
    __threadfence();
    __syncthreads();
    __shared__ int lastf;
    int patch = ex * 7 + iy;
    if (lid == 0) lastf = (atomicAdd(&cnt[patch], 1) == KC2 - 1) ? 1 : 0;
    __syncthreads();
    if (!lastf) return;
    __threadfence();
    patch_update<true>(W, W, part, dbuf, rs, ex, iy, lid);
    if (lid == 0) cnt[patch] = 0;   // reset for next launch/replay
}

extern "C" void kernel_launch(void* const* d_in, const int* in_sizes, int n_in,
                              void* d_out, int out_size, void* d_ws, size_t ws_size,
                              hipStream_t stream) {
    const float* x     = (const float*)d_in[0];  // (50, 512, 784)
    const float* W_ine = (const float*)d_in[1];  // (400, 784)

    float* p = (float*)d_ws;
    float* W_cur = p; p += NE * NIN;
    float* dbuf  = p; p += NE;
    float* rs    = p; p += 7 * NE;
    int*   cnt   = (int*)p; p += 64;
    float* dgp   = p; p += (size_t)KC1 * BB * NE;
    float* part  = p; p += (size_t)KC2 * NE * NIN;
    float* A1s   = p; p += BB * NE;
    float* A2s   = p; p += BB * NE;
    float* g_ine = p; p += BB * NE;
    float* g_ei  = p; p += BB * NE;
    float* g_ie  = p; p += BB * NE;
    float* Iie   = p; p += BB * NE;
    float* mem_e = p; p += BB * NE;
    float* rc_e  = p; p += BB * NE;
    float* mem_i = p; p += BB * NE;
    float* rc_i  = p; p += BB * NE;
    float* theta = p; p += BB * NE;
    float* tp1   = p; p += BB * NE;
    float* tp2   = p; p += BB * NE;
    float* tr    = p; p += BB * NIN;

    k_init<<<800 + NPATCH + 196, 256, 0, stream>>>(W_ine, W_cur, rs, cnt, x, tr,
                                                   g_ine, g_ei, g_ie, Iie, mem_e,
                                                   rc_e, mem_i, rc_i, theta, tp1, tp2);

    for (int t = 0; t < TT; t++) {
        const float* xt = x + (size_t)t * BB * NIN;
        float* out_t = (float*)d_out + (size_t)t * BB * NE;
        k_g1<<<588, 256, 0, stream>>>(xt, W_cur, dgp, tr, t);
        k_mid<<<BB, 512, 0, stream>>>(dgp, rs, dbuf, g_ine, g_ei, g_ie,
                                      Iie, mem_e, rc_e, mem_i, rc_i, theta,
                                      tp1, tp2, A1s, A2s, out_t);
        if (t < TT - 1)
            k_g2f<<<dim3(7, 7, KC2), 256, 0, stream>>>(A1s, A2s, xt, tr, part,
                                                       W_cur, dbuf, rs, cnt);
    }
}